// Round 1
// baseline (326.311 us; speedup 1.0000x reference)
//
#include <hip/hip_runtime.h>

#define N_LABELS 45
#define N_TRIGRAMS 4000000

// Build lower-bound offsets: offsets[w] = first i with seg[i] >= w, offsets[W] = F.
// seg is sorted ascending. Each offsets slot is written exactly once.
__global__ void build_offsets_kernel(const int* __restrict__ seg,
                                     int* __restrict__ off, int F, int W) {
    int i = blockIdx.x * blockDim.x + threadIdx.x;
    if (i >= F) return;
    int s = seg[i];
    int p = (i == 0) ? -1 : seg[i - 1];
    // words whose first entry is i
    for (int w = p + 1; w <= s; ++w) off[w] = i;
    if (i == F - 1) {
        // words past the last segment id (empty), plus the terminator
        for (int w = s + 1; w <= W; ++w) off[w] = F;
    }
}

// One wave (64 lanes) per word. Lanes 0..44 own label columns.
__global__ void tagger_kernel(const int* __restrict__ feat,
                              const float* __restrict__ weights,
                              const float* __restrict__ trigram_w,
                              const int* __restrict__ off,
                              float* __restrict__ out, int W) {
    int wave = (int)((blockIdx.x * blockDim.x + threadIdx.x) >> 6);
    int lane = (int)(threadIdx.x & 63);
    if (wave >= W) return;

    int beg = off[wave];
    int end = off[wave + 1];

    float acc = 0.0f;
    long long tri = 0;

    for (int base = beg; base < end; base += 64) {
        int cnt = min(64, end - base);
        // one coalesced load of up to 64 indices for this word
        int my = (lane < cnt) ? feat[base + lane] : 0;
        for (int e = 0; e < cnt; ++e) {
            int idx = __shfl(my, e, 64);
            tri += (long long)idx;
            if (lane < N_LABELS)
                acc += weights[(long long)idx * N_LABELS + lane];
        }
    }

    // trigram gather with JAX clip semantics
    long long t = tri;
    if (t < 0) t = 0;
    if (t >= N_TRIGRAMS) t = N_TRIGRAMS - 1;
    float trig = trigram_w[t];

    if (lane < N_LABELS)
        out[(long long)wave * N_LABELS + lane] = acc + trig;
}

extern "C" void kernel_launch(void* const* d_in, const int* in_sizes, int n_in,
                              void* d_out, int out_size, void* d_ws, size_t ws_size,
                              hipStream_t stream) {
    const int*   feat      = (const int*)d_in[0];     // feat_indices [F]
    const int*   seg       = (const int*)d_in[1];     // segment_ids  [F], sorted
    const float* weights   = (const float*)d_in[2];   // [N_FEATURES, 45]
    const float* trigram_w = (const float*)d_in[3];   // [N_TRIGRAMS]
    float*       out       = (float*)d_out;           // [W, 45]

    int F = in_sizes[0];
    int W = out_size / N_LABELS;

    int* off = (int*)d_ws;  // (W+1) ints

    {
        int threads = 256;
        int blocks = (F + threads - 1) / threads;
        build_offsets_kernel<<<blocks, threads, 0, stream>>>(seg, off, F, W);
    }
    {
        int threads = 256;              // 4 waves per block
        int wavesPerBlock = threads / 64;
        int blocks = (W + wavesPerBlock - 1) / wavesPerBlock;
        tagger_kernel<<<blocks, threads, 0, stream>>>(feat, weights, trigram_w,
                                                      off, out, W);
    }
}

// Round 2
// 214.410 us; speedup vs baseline: 1.5219x; 1.5219x over previous
//
#include <hip/hip_runtime.h>

#define N_LABELS 45
#define N_TRIGRAMS 4000000

// Build lower-bound offsets: off[w] = first i with seg[i] >= w, off[W] = F.
__global__ void build_offsets_kernel(const int* __restrict__ seg,
                                     int* __restrict__ off, int F, int W) {
    int i = blockIdx.x * blockDim.x + threadIdx.x;
    if (i >= F) return;
    int s = seg[i];
    int p = (i == 0) ? -1 : seg[i - 1];
    for (int w = p + 1; w <= s; ++w) off[w] = i;
    if (i == F - 1) {
        for (int w = s + 1; w <= W; ++w) off[w] = F;
    }
}

// One wave (64 lanes) per word. Lanes 0..44 own label columns.
__global__ void tagger_kernel(const int* __restrict__ feat,
                              const float* __restrict__ weights,
                              const float* __restrict__ trigram_w,
                              const int* __restrict__ off,
                              float* __restrict__ out, int W) {
    int wave = (int)((blockIdx.x * blockDim.x + threadIdx.x) >> 6);
    int lane = (int)(threadIdx.x & 63);
    if (wave >= W) return;

    int beg = off[wave];
    int end = off[wave + 1];

    int ll = (lane < N_LABELS) ? lane : 0;   // clamp: lanes 45..63 mirror lane 0 (no OOB)

    float acc = 0.0f;
    int tri = 0;

    for (int base = beg; base < end; base += 64) {
        int cnt = min(64, end - base);

        // one coalesced load of this word's indices
        int my = feat[base + ((lane < cnt) ? lane : 0)];

        // trigram index: butterfly-reduce the (masked) indices across the wave
        int mv = (lane < cnt) ? my : 0;
        #pragma unroll
        for (int s = 1; s < 64; s <<= 1) mv += __shfl_xor(mv, s, 64);
        tri += mv;

        int idx0 = __builtin_amdgcn_readfirstlane(my);

        // gather weight rows in groups of 8 independent loads (MLP)
        for (int g = 0; g < cnt; g += 8) {
            float v[8];
            #pragma unroll
            for (int j = 0; j < 8; ++j) {
                int e = g + j;                               // wave-uniform
                int idx = (e < cnt) ? __builtin_amdgcn_readlane(my, e) : idx0;
                v[j] = weights[idx * N_LABELS + ll];
            }
            #pragma unroll
            for (int j = 0; j < 8; ++j) {
                if (g + j < cnt) acc += v[j];                // scalar predicate
            }
        }
    }

    // trigram gather with JAX clip semantics (tri fits in int: < 64 * 500000)
    int t = tri;
    if (t < 0) t = 0;
    if (t >= N_TRIGRAMS) t = N_TRIGRAMS - 1;
    float trig = trigram_w[t];

    if (lane < N_LABELS)
        out[(long long)wave * N_LABELS + lane] = acc + trig;
}

extern "C" void kernel_launch(void* const* d_in, const int* in_sizes, int n_in,
                              void* d_out, int out_size, void* d_ws, size_t ws_size,
                              hipStream_t stream) {
    const int*   feat      = (const int*)d_in[0];
    const int*   seg       = (const int*)d_in[1];
    const float* weights   = (const float*)d_in[2];
    const float* trigram_w = (const float*)d_in[3];
    float*       out       = (float*)d_out;

    int F = in_sizes[0];
    int W = out_size / N_LABELS;

    int* off = (int*)d_ws;  // (W+1) ints

    {
        int threads = 256;
        int blocks = (F + threads - 1) / threads;
        build_offsets_kernel<<<blocks, threads, 0, stream>>>(seg, off, F, W);
    }
    {
        int threads = 256;  // 4 waves per block
        int wavesPerBlock = threads / 64;
        int blocks = (W + wavesPerBlock - 1) / wavesPerBlock;
        tagger_kernel<<<blocks, threads, 0, stream>>>(feat, weights, trigram_w,
                                                      off, out, W);
    }
}

// Round 3
// 196.603 us; speedup vs baseline: 1.6597x; 1.0906x over previous
//
#include <hip/hip_runtime.h>

#define N_LABELS 45
#define N_TRIGRAMS 4000000

// Build lower-bound offsets: off[w] = first i with seg[i] >= w, off[W] = F.
__global__ void build_offsets_kernel(const int* __restrict__ seg,
                                     int* __restrict__ off, int F, int W) {
    int i = blockIdx.x * blockDim.x + threadIdx.x;
    if (i >= F) return;
    int s = seg[i];
    int p = (i == 0) ? -1 : seg[i - 1];
    for (int w = p + 1; w <= s; ++w) off[w] = i;
    if (i == F - 1) {
        for (int w = s + 1; w <= W; ++w) off[w] = F;
    }
}

// One wave (64 lanes) per word. Lanes 0..44 own label columns.
__global__ void tagger_kernel(const int* __restrict__ feat,
                              const float* __restrict__ weights,
                              const float* __restrict__ trigram_w,
                              const int* __restrict__ off,
                              float* __restrict__ out, int W) {
    int wave = (int)((blockIdx.x * blockDim.x + threadIdx.x) >> 6);
    int lane = (int)(threadIdx.x & 63);
    if (wave >= W) return;
    wave = __builtin_amdgcn_readfirstlane(wave);   // help uniformity analysis

    int beg = off[wave];
    int end = off[wave + 1];

    int ll = (lane < N_LABELS) ? lane : 0;   // lanes 45..63 mirror lane 0

    float acc = 0.0f;
    int tri = 0;                              // stays in SGPR (all inputs uniform)

    for (int base = beg; base < end; base += 64) {
        int cnt = min(64, end - base);        // uniform, >= 1

        // one coalesced load of this word's indices
        int my = feat[base + ((lane < cnt) ? lane : 0)];

        for (int g = 0; g < cnt; g += 8) {
            float v[8];
            #pragma unroll
            for (int j = 0; j < 8; ++j) {
                int e = g + j;                          // uniform
                int ec = (e < cnt) ? e : (cnt - 1);     // clamp to last valid entry
                int idx = __builtin_amdgcn_readlane(my, ec);  // SGPR
                tri += (e < cnt) ? idx : 0;             // scalar-side trigram sum
                const float* row = weights + (unsigned)idx * N_LABELS; // scalar ptr
                v[j] = row[ll];                         // saddr + const voffset
            }
            // pad slots all duplicated v[7] (clamped to cnt-1); correct once.
            int pad = (g + 8 > cnt) ? (g + 8 - cnt) : 0;
            float s01 = v[0] + v[1], s23 = v[2] + v[3];
            float s45 = v[4] + v[5], s67 = v[6] + v[7];
            float sum = (s01 + s23) + (s45 + s67);
            acc += sum - (float)pad * v[7];
        }
    }

    // trigram gather with JAX clip semantics
    int t = tri;
    if (t < 0) t = 0;
    if (t >= N_TRIGRAMS) t = N_TRIGRAMS - 1;
    float trig = trigram_w[t];

    if (lane < N_LABELS)
        out[(long long)wave * N_LABELS + lane] = acc + trig;
}

extern "C" void kernel_launch(void* const* d_in, const int* in_sizes, int n_in,
                              void* d_out, int out_size, void* d_ws, size_t ws_size,
                              hipStream_t stream) {
    const int*   feat      = (const int*)d_in[0];
    const int*   seg       = (const int*)d_in[1];
    const float* weights   = (const float*)d_in[2];
    const float* trigram_w = (const float*)d_in[3];
    float*       out       = (float*)d_out;

    int F = in_sizes[0];
    int W = out_size / N_LABELS;

    int* off = (int*)d_ws;  // (W+1) ints

    {
        int threads = 256;
        int blocks = (F + threads - 1) / threads;
        build_offsets_kernel<<<blocks, threads, 0, stream>>>(seg, off, F, W);
    }
    {
        int threads = 256;  // 4 waves per block
        int wavesPerBlock = threads / 64;
        int blocks = (W + wavesPerBlock - 1) / wavesPerBlock;
        tagger_kernel<<<blocks, threads, 0, stream>>>(feat, weights, trigram_w,
                                                      off, out, W);
    }
}

// Round 4
// 185.863 us; speedup vs baseline: 1.7557x; 1.0578x over previous
//
#include <hip/hip_runtime.h>

#define N_LABELS 45
#define N_TRIGRAMS 4000000
#define WPW 4     // words per wave
#define GRP 16    // clamped gather group per word (P[len>16] ~ 0.6%)

// Build lower-bound offsets: off[w] = first i with seg[i] >= w, off[W] = F.
__global__ void build_offsets_kernel(const int* __restrict__ seg,
                                     int* __restrict__ off, int F, int W) {
    int i = blockIdx.x * blockDim.x + threadIdx.x;
    if (i >= F) return;
    int s = seg[i];
    int p = (i == 0) ? -1 : seg[i - 1];
    for (int w = p + 1; w <= s; ++w) off[w] = i;
    if (i == F - 1) {
        for (int w = s + 1; w <= W; ++w) off[w] = F;
    }
}

// One wave per WPW consecutive words. Lanes 0..44 own label columns.
// Since seg is sorted, the WPW words' entries are one contiguous feat range:
// a single 64-entry coalesced chunk load feeds (almost) all gathers.
__global__ void tagger_kernel(const int* __restrict__ feat,
                              const float* __restrict__ weights,
                              const float* __restrict__ trigram_w,
                              const int* __restrict__ off,
                              float* __restrict__ out, int W, int F) {
    int gwave = (int)((blockIdx.x * blockDim.x + threadIdx.x) >> 6);
    gwave = __builtin_amdgcn_readfirstlane(gwave);
    int lane = (int)(threadIdx.x & 63);
    int w0 = gwave * WPW;
    if (w0 >= W) return;

    int ll = (lane < N_LABELS) ? lane : 0;   // lanes 45..63 mirror lane 0

    // word boundaries (wave-uniform -> scalar loads)
    int b[WPW + 1];
    #pragma unroll
    for (int k = 0; k <= WPW; ++k) {
        int w = w0 + k;
        b[k] = off[(w < W) ? w : W];
    }

    int beg = b[0];
    // one coalesced chunk of up to 64 indices covering all WPW words
    int my = feat[min(beg + lane, F - 1)];

    float acc[WPW];
    int   tri[WPW];
    float vals[WPW][GRP];

    // ---- issue phase: branch-free, all 4*GRP gathers in flight ----
    #pragma unroll
    for (int k = 0; k < WPW; ++k) {
        int s = b[k], e = b[k + 1];
        int len = e - s;
        int rel = s - beg;                         // >= 0
        int avail = 64 - min(rel, 64);             // chunk slots usable
        int ncov = min(min(len, GRP), avail);      // fast-covered entries
        int lastj = (ncov > 0) ? (ncov - 1) : 0;
        tri[k] = 0;
        acc[k] = 0.0f;
        #pragma unroll
        for (int j = 0; j < GRP; ++j) {
            int p = rel + ((j < ncov) ? j : lastj); // pads duplicate last entry
            p = min(p, 63);
            int idx = __builtin_amdgcn_readlane(my, p);   // SGPR
            tri[k] += (j < ncov) ? idx : 0;
            const float* row = weights + (unsigned)idx * N_LABELS;
            vals[k][j] = row[ll];
        }
    }

    float trig[WPW];

    // ---- consume phase ----
    #pragma unroll
    for (int k = 0; k < WPW; ++k) {
        int s = b[k], e = b[k + 1];
        int len = e - s;
        int rel = s - beg;
        int avail = 64 - min(rel, 64);
        int ncov = min(min(len, GRP), avail);
        int pad = GRP - ncov;

        float t0 = (vals[k][0]  + vals[k][1])  + (vals[k][2]  + vals[k][3]);
        float t1 = (vals[k][4]  + vals[k][5])  + (vals[k][6]  + vals[k][7]);
        float t2 = (vals[k][8]  + vals[k][9])  + (vals[k][10] + vals[k][11]);
        float t3 = (vals[k][12] + vals[k][13]) + (vals[k][14] + vals[k][15]);
        float sum = (t0 + t1) + (t2 + t3);
        // padded slots all duplicated vals[k][GRP-1]; subtract them once
        acc[k] += sum - (float)pad * vals[k][GRP - 1];

        // slow remainder: len > GRP or chunk overflow (rare)
        if (s + ncov < e) {
            for (int base2 = s + ncov; base2 < e; base2 += 64) {
                int cnt = min(64, e - base2);
                int m2 = feat[base2 + ((lane < cnt) ? lane : 0)];
                for (int g = 0; g < cnt; g += 8) {
                    float v2[8];
                    int lastE = cnt - 1;
                    #pragma unroll
                    for (int j = 0; j < 8; ++j) {
                        int e2 = g + j;
                        int ec = (e2 < cnt) ? e2 : lastE;
                        int idx = __builtin_amdgcn_readlane(m2, ec);
                        tri[k] += (e2 < cnt) ? idx : 0;
                        const float* row = weights + (unsigned)idx * N_LABELS;
                        v2[j] = row[ll];
                    }
                    int pad2 = (g + 8 > cnt) ? (g + 8 - cnt) : 0;
                    float s01 = v2[0] + v2[1], s23 = v2[2] + v2[3];
                    float s45 = v2[4] + v2[5], s67 = v2[6] + v2[7];
                    acc[k] += ((s01 + s23) + (s45 + s67)) - (float)pad2 * v2[7];
                }
            }
        }

        // trigram gather (JAX clip semantics); issue early, consume at store
        int t = tri[k];
        if (t < 0) t = 0;
        if (t >= N_TRIGRAMS) t = N_TRIGRAMS - 1;
        trig[k] = trigram_w[t];
    }

    #pragma unroll
    for (int k = 0; k < WPW; ++k) {
        int w = w0 + k;
        if (lane < N_LABELS && w < W)
            out[(long long)w * N_LABELS + lane] = acc[k] + trig[k];
    }
}

extern "C" void kernel_launch(void* const* d_in, const int* in_sizes, int n_in,
                              void* d_out, int out_size, void* d_ws, size_t ws_size,
                              hipStream_t stream) {
    const int*   feat      = (const int*)d_in[0];
    const int*   seg       = (const int*)d_in[1];
    const float* weights   = (const float*)d_in[2];
    const float* trigram_w = (const float*)d_in[3];
    float*       out       = (float*)d_out;

    int F = in_sizes[0];
    int W = out_size / N_LABELS;

    int* off = (int*)d_ws;  // (W+1) ints

    {
        int threads = 256;
        int blocks = (F + threads - 1) / threads;
        build_offsets_kernel<<<blocks, threads, 0, stream>>>(seg, off, F, W);
    }
    {
        int threads = 256;  // 4 waves per block
        int wavesPerBlock = threads / 64;
        int nWaves = (W + WPW - 1) / WPW;
        int blocks = (nWaves + wavesPerBlock - 1) / wavesPerBlock;
        tagger_kernel<<<blocks, threads, 0, stream>>>(feat, weights, trigram_w,
                                                      off, out, W, F);
    }
}